// Round 2
// baseline (1201.243 us; speedup 1.0000x reference)
//
#include <hip/hip_runtime.h>
#include <hip/hip_bf16.h>

// Problem constants (match reference setup_inputs)
#define BB 256
#define TT 200
#define QQ 2048
#define ROWS (BB * (TT - 1))   // 50944 contributing (b, t>=1) rows

// Kernel 1: one block per (b, t) row with t in [1, T).
// Scan the 4096-float one-hot row of `batch` to find the nonzero position,
// derive (qid, correct), gather p = pred[b, t-1, qid], emit the per-row
// -bce term into partial[].
__global__ __launch_bounds__(256) void row_bce_kernel(
    const float* __restrict__ pred,
    const float* __restrict__ batch,
    float* __restrict__ partial) {
    const int blk = blockIdx.x;          // 0 .. ROWS-1
    const int b = blk / (TT - 1);
    const int t = blk % (TT - 1) + 1;    // t in [1, T)
    const float4* row = reinterpret_cast<const float4*>(
        batch + ((size_t)b * TT + t) * (2 * QQ));
    const int tid = threadIdx.x;

    __shared__ int s_pos;
    if (tid == 0) s_pos = -1;
    __syncthreads();

    int found = -1;
    #pragma unroll
    for (int k = 0; k < 4; ++k) {
        const int idx4 = k * 256 + tid;      // float4 index within the row
        float4 v = row[idx4];
        if (v.x > 0.5f) found = idx4 * 4 + 0;
        if (v.y > 0.5f) found = idx4 * 4 + 1;
        if (v.z > 0.5f) found = idx4 * 4 + 2;
        if (v.w > 0.5f) found = idx4 * 4 + 3;
    }
    if (found >= 0) atomicMax(&s_pos, found);
    __syncthreads();

    if (tid == 0) {
        const int pos = s_pos;               // exactly one per row
        const bool correct = pos < QQ;
        const int qid = correct ? pos : pos - QQ;
        const float p = pred[((size_t)b * TT + (t - 1)) * QQ + qid];
        const float bce = correct ? logf(p) : log1pf(-p);
        partial[blk] = -bce;
    }
}

// Kernel 2: single-block deterministic reduction of the ROWS partials.
__global__ __launch_bounds__(1024) void reduce_kernel(
    const float* __restrict__ partial,
    float* __restrict__ out) {
    float s = 0.0f;
    for (int i = threadIdx.x; i < ROWS; i += 1024) s += partial[i];
    // wave (64-lane) reduce
    #pragma unroll
    for (int off = 32; off > 0; off >>= 1) s += __shfl_down(s, off, 64);
    __shared__ float ws[16];
    const int wave = threadIdx.x >> 6;
    if ((threadIdx.x & 63) == 0) ws[wave] = s;
    __syncthreads();
    if (threadIdx.x == 0) {
        float tot = 0.0f;
        #pragma unroll
        for (int w = 0; w < 16; ++w) tot += ws[w];
        out[0] = tot;
    }
}

extern "C" void kernel_launch(void* const* d_in, const int* in_sizes, int n_in,
                              void* d_out, int out_size, void* d_ws, size_t ws_size,
                              hipStream_t stream) {
    const float* pred  = (const float*)d_in[0];   // [B, T, Q] fp32
    const float* batch = (const float*)d_in[1];   // [B, T, 2Q] fp32
    float* out = (float*)d_out;                   // scalar loss
    float* partial = (float*)d_ws;                // ROWS floats (~204 KB)

    row_bce_kernel<<<ROWS, 256, 0, stream>>>(pred, batch, partial);
    reduce_kernel<<<1, 1024, 0, stream>>>(partial, out);
}